// Round 1
// baseline (422.918 us; speedup 1.0000x reference)
//
#include <hip/hip_runtime.h>

// RSTDP update, algebraically reduced:
//   mask[o][i] = post_sp[o]>0.5 && pre_sp[i]>0.5
//   where mask holds, dts = current_time - current_time = 0  ->  dw = -A_MINUS
//   out = clip(weight + reward * dw * mask, -1, 1)
// Pure streaming op: 256 MB read + 256 MB write, memory-bound.

#define N_IN  8192
#define N_OUT 8192
#define A_MINUS 0.012f

__global__ __launch_bounds__(256) void rstdp_kernel(
    const float4* __restrict__ w,      // weight, (N_OUT*N_IN/4) float4
    const float*  __restrict__ pre,    // pre_spikes  (N_IN)
    const float*  __restrict__ post,   // post_spikes (N_OUT)
    const float*  __restrict__ reward, // scalar
    float4* __restrict__ out)
{
    const unsigned gid  = blockIdx.x * blockDim.x + threadIdx.x;
    const unsigned row  = gid >> 11;        // 8192/4 = 2048 float4 per row
    const unsigned col4 = gid & 2047;

    const float rdelta = reward[0] * (-A_MINUS);   // uniform (s_load)
    const bool post_act = post[row] > 0.5f;        // wave-mostly-uniform, L1 broadcast

    const float4 pre4 = ((const float4*)pre)[col4]; // 32 KB vector, L1-resident
    float4 wv = w[gid];

    const float d0 = (post_act && pre4.x > 0.5f) ? rdelta : 0.0f;
    const float d1 = (post_act && pre4.y > 0.5f) ? rdelta : 0.0f;
    const float d2 = (post_act && pre4.z > 0.5f) ? rdelta : 0.0f;
    const float d3 = (post_act && pre4.w > 0.5f) ? rdelta : 0.0f;

    wv.x = fminf(fmaxf(wv.x + d0, -1.0f), 1.0f);
    wv.y = fminf(fmaxf(wv.y + d1, -1.0f), 1.0f);
    wv.z = fminf(fmaxf(wv.z + d2, -1.0f), 1.0f);
    wv.w = fminf(fmaxf(wv.w + d3, -1.0f), 1.0f);

    out[gid] = wv;
}

extern "C" void kernel_launch(void* const* d_in, const int* in_sizes, int n_in,
                              void* d_out, int out_size, void* d_ws, size_t ws_size,
                              hipStream_t stream) {
    // Inputs in setup_inputs() order:
    // 0: weight (N_OUT*N_IN f32), 1: pre_spikes (N_IN), 2: post_spikes (N_OUT),
    // 3: reward (1), 4: pre_times (N_IN, unused), 5: post_times (N_OUT, unused)
    const float4* w      = (const float4*)d_in[0];
    const float*  pre    = (const float*)d_in[1];
    const float*  post   = (const float*)d_in[2];
    const float*  reward = (const float*)d_in[3];
    float4* out = (float4*)d_out;

    const int total4 = (N_OUT * N_IN) / 4;   // 16,777,216
    const int block  = 256;
    const int grid   = total4 / block;       // 65,536

    rstdp_kernel<<<grid, block, 0, stream>>>(w, pre, post, reward, out);
}